// Round 6
// baseline (1901.070 us; speedup 1.0000x reference)
//
#include <hip/hip_runtime.h>

// Problem constants (match reference)
constexpr int NB   = 8;     // batches
constexpr int NC   = 64;    // channels
constexpr int NN   = 8192;  // points
constexpr int NM   = 2048;  // samples
constexpr int NK   = 16;    // knn
constexpr int NFPS = 1433;  // int(2048*0.7)
constexpr int NRAND = NM - NFPS; // 615

// ---------------- workspace layout (bytes) ----------------
constexpr size_t OFF_IDX   = 256;      // int idx[8][2048]
constexpr size_t OFF_V1    = 66048;    // uint v1[8][8192]
constexpr size_t OFF_KNN   = 328448;   // int knn[8][2048][16]
constexpr size_t OFF_XT    = 1377280;  // float xT[8][8192][64]

typedef float v2f __attribute__((ext_vector_type(2)));

struct TF { unsigned a, b; };

__device__ __forceinline__ TF tf2(unsigned k0, unsigned k1, unsigned c0, unsigned c1) {
  unsigned ks2 = k0 ^ k1 ^ 0x1BD11BDAu;
  unsigned x0 = c0 + k0;
  unsigned x1 = c1 + k1;
#define TF_R(r) { x0 += x1; x1 = (x1 << r) | (x1 >> (32 - r)); x1 ^= x0; }
  TF_R(13) TF_R(15) TF_R(26) TF_R(6)
  x0 += k1;  x1 += ks2 + 1u;
  TF_R(17) TF_R(29) TF_R(16) TF_R(24)
  x0 += ks2; x1 += k0 + 2u;
  TF_R(13) TF_R(15) TF_R(26) TF_R(6)
  x0 += k0;  x1 += k1 + 3u;
  TF_R(17) TF_R(29) TF_R(16) TF_R(24)
  x0 += k1;  x1 += ks2 + 4u;
  TF_R(13) TF_R(15) TF_R(26) TF_R(6)
  x0 += ks2; x1 += k0 + 5u;
#undef TF_R
  TF r; r.a = x0; r.b = x1; return r;
}

// DPP-based wave64 max (VALU latency, no LDS on the chain).
__device__ __forceinline__ float wave_max_dpp(float v) {
  int vi;
  vi = __builtin_amdgcn_update_dpp(__float_as_int(v), __float_as_int(v), 0x111, 0xf, 0xf, false);
  v = fmaxf(v, __int_as_float(vi));
  vi = __builtin_amdgcn_update_dpp(__float_as_int(v), __float_as_int(v), 0x112, 0xf, 0xf, false);
  v = fmaxf(v, __int_as_float(vi));
  vi = __builtin_amdgcn_update_dpp(__float_as_int(v), __float_as_int(v), 0x114, 0xf, 0xf, false);
  v = fmaxf(v, __int_as_float(vi));
  vi = __builtin_amdgcn_update_dpp(__float_as_int(v), __float_as_int(v), 0x118, 0xf, 0xf, false);
  v = fmaxf(v, __int_as_float(vi));
  vi = __builtin_amdgcn_update_dpp(__float_as_int(v), __float_as_int(v), 0x142, 0xa, 0xf, false);
  v = fmaxf(v, __int_as_float(vi));
  vi = __builtin_amdgcn_update_dpp(__float_as_int(v), __float_as_int(v), 0x143, 0xc, 0xf, false);
  v = fmaxf(v, __int_as_float(vi));
  return __int_as_float(__builtin_amdgcn_readlane(__float_as_int(v), 63));
}

// ---------------- fused1: fps (blocks 0-7) + perm (8-23) + transpose (24-4119) ----
// fps occupies only 8 CUs for ~1.2 ms; perm and transpose have NO dependence
// on fps (disjoint outputs) and stream through the other 248 CUs inside fps's
// shadow. No inter-block communication -> dispatch-order independent (G16).
constexpr int FPS_BLKS = NB;                 // 8
constexpr int PERM_BLKS = 2 * NB;            // 16
constexpr int TR_BLKS = (NN / 32) * (NC / 32) * NB;  // 4096

// smem layout (bytes): fps uses 0..104196; perm uses 0..65536; transpose 4.2KB
constexpr int SM_SLOTC = 98304;   // float4 slotC[2][4]  (128 B)
constexpr int SM_SLOTI = 98432;   // int    slotI[2][4]  (32 B)
constexpr int SM_IDXB  = 98464;   // int    idxBuf[NFPS] (5732 B)
constexpr int SM_TOTAL = 104208;

// bitonic sort over 8192 u64 in LDS, 256 threads (16 pairs/thread/stage)
__device__ void bitonic8192_256(unsigned long long* s, int tid) {
  for (unsigned k = 2; k <= 8192u; k <<= 1) {
    for (unsigned j = k >> 1; j > 0; j >>= 1) {
      __syncthreads();
      for (unsigned t = (unsigned)tid; t < 4096u; t += 256u) {
        unsigned i = ((t & ~(j - 1u)) << 1) | (t & (j - 1u));
        unsigned p = i | j;
        bool up = ((i & k) == 0u);
        unsigned long long a = s[i], c = s[p];
        if ((a > c) == up) { s[i] = c; s[p] = a; }
      }
    }
  }
  __syncthreads();
}

__global__ __launch_bounds__(256, 1) void fused1_kernel(const float* __restrict__ pos,
                                                        const float* __restrict__ x,
                                                        int* __restrict__ idx,
                                                        unsigned* __restrict__ v1buf,
                                                        float* __restrict__ xT) {
  __shared__ __align__(16) char smem[SM_TOTAL];
  const int bid = blockIdx.x;
  const int tid = threadIdx.x;

  if (bid < FPS_BLKS) {
    // ================= FPS (256 thr, 4 waves; R0 skeleton + pk math) ===========
    float* ldsX = (float*)smem;                       // 32 KB
    float* ldsY = (float*)(smem + 32768);             // 32 KB
    float* ldsZ = (float*)(smem + 65536);             // 32 KB
    float4 (*slotC)[4] = (float4(*)[4])(smem + SM_SLOTC); // [2][4] {wm,x,y,z}
    int    (*slotI)[4] = (int(*)[4])(smem + SM_SLOTI);    // [2][4] idx
    int*   idxB = (int*)(smem + SM_IDXB);                 // [NFPS]
    const int b = bid;
    const int wv = tid >> 6, lane = tid & 63;
    const float* pb = pos + (size_t)b * 3 * NN;
    v2f px[16], py[16], pz[16], dist[16];   // 32 points as 16 pairs
    const int base = tid * 32;   // tid-major ownership => lane order == index order
    const float4* fx = (const float4*)(pb + base);
    const float4* fy = (const float4*)(pb + NN + base);
    const float4* fz = (const float4*)(pb + 2 * NN + base);
#pragma unroll
    for (int q = 0; q < 8; ++q) {
      float4 a = fx[q], c = fy[q], e = fz[q];
      px[2*q].x = a.x; px[2*q].y = a.y; px[2*q+1].x = a.z; px[2*q+1].y = a.w;
      py[2*q].x = c.x; py[2*q].y = c.y; py[2*q+1].x = c.z; py[2*q+1].y = c.w;
      pz[2*q].x = e.x; pz[2*q].y = e.y; pz[2*q+1].x = e.z; pz[2*q+1].y = e.w;
      ((float4*)(ldsX + base))[q] = a;   // one-time stage
      ((float4*)(ldsY + base))[q] = c;
      ((float4*)(ldsZ + base))[q] = e;
    }
#pragma unroll
    for (int p = 0; p < 16; ++p) { dist[p].x = 1e10f; dist[p].y = 1e10f; }
    // inline start index: jax.random.key(42) -> keys[b] -> randint
    TF kb_ = tf2(0u, 42u, 0u, (unsigned)b);
    TF k2 = tf2(kb_.a, kb_.b, 0u, 1u);
    TF bt = tf2(k2.a, k2.b, 0u, 0u);
    int widx = (int)((bt.a ^ bt.b) & (unsigned)(NN - 1));
    if (tid == 0) idxB[0] = widx;
    __syncthreads();
    float cx = ldsX[widx], cy = ldsY[widx], cz = ldsZ[widx];
    for (int it = 1; it < NFPS; ++it) {
      const int par = it & 1;
      float bestv = -1.0f; int bestS = 0;
      {
        v2f cx2; cx2.x = cx; cx2.y = cx;
        v2f cy2; cy2.x = cy; cy2.y = cy;
        v2f cz2; cz2.x = cz; cz2.y = cz;
#pragma unroll
        for (int p = 0; p < 16; ++p) {
          // Mirror numpy/XLA exactly per half: rn ops, NO fma contraction,
          // ((dx2+dy2)+dz2). contract(off) keeps pk_mul/pk_add separate.
          // (bit-exactness of this packed form verified by R3's passing run)
#pragma clang fp contract(off)
          v2f dx = px[p] - cx2;
          v2f dy = py[p] - cy2;
          v2f dz = pz[p] - cz2;
          v2f d2 = (dx * dx + dy * dy) + dz * dz;
          float nd0 = fminf(dist[p].x, d2.x);
          float nd1 = fminf(dist[p].y, d2.y);
          dist[p].x = nd0; dist[p].y = nd1;
          // per-slot tracking, ascending slot order (2p, 2p+1), strict >
          bool c0 = nd0 > bestv;
          bestv = c0 ? nd0 : bestv;
          bestS = c0 ? 2*p : bestS;
          bool c1 = nd1 > bestv;
          bestv = c1 ? nd1 : bestv;
          bestS = c1 ? 2*p + 1 : bestS;
        }
      }
      const int gidx = base + bestS;
      // speculative read of OWN candidate coords; latency hides under DPP chain
      const float ox = ldsX[gidx], oy = ldsY[gidx], oz = ldsZ[gidx];
      const float wm = wave_max_dpp(bestv);
      unsigned long long msk = __ballot(bestv == wm);  // nonzero: max lane matches
      const int fl = (int)__builtin_ctzll(msk);        // lowest lane = smallest index
      const int widxw = __builtin_amdgcn_readlane(gidx, fl);
      const float wx = __int_as_float(__builtin_amdgcn_readlane(__float_as_int(ox), fl));
      const float wy = __int_as_float(__builtin_amdgcn_readlane(__float_as_int(oy), fl));
      const float wz = __int_as_float(__builtin_amdgcn_readlane(__float_as_int(oz), fl));
      if (lane == 0) {
        slotC[par][wv] = make_float4(wm, wx, wy, wz);
        slotI[par][wv] = widxw;
      }
      __syncthreads();
      // block merge: coords + idx carried with the value -> no 2nd LDS trip.
      float4 q0 = slotC[par][0], q1 = slotC[par][1], q2 = slotC[par][2], q3 = slotC[par][3];
      int i0 = slotI[par][0], i1 = slotI[par][1], i2 = slotI[par][2], i3 = slotI[par][3];
      if (q1.x > q0.x) { q0 = q1; i0 = i1; }   // ties keep lower wave = smaller index
      if (q3.x > q2.x) { q2 = q3; i2 = i3; }
      if (q2.x > q0.x) { q0 = q2; i0 = i2; }
      widx = i0; cx = q0.y; cy = q0.z; cz = q0.w;
      if (tid == 0) idxB[it] = widx;   // LDS, no global-store drain at barrier
    }
    __syncthreads();
    for (int i = tid; i < NFPS; i += 256) idx[b * NM + i] = idxB[i];  // coalesced flush
  } else if (bid < FPS_BLKS + PERM_BLKS) {
    // ================= permutation sorts (round 0: v1, round 1: rand idx) =======
    unsigned long long* s = (unsigned long long*)smem; // 64 KB
    const int pbl = bid - FPS_BLKS;
    const int b = pbl >> 1, r = pbl & 1;
    TF keyr = tf2(0u, 42u, 0u, 1u);
    TF rk = tf2(keyr.a, keyr.b, 0u, (unsigned)b);
    TF s1k = tf2(rk.a, rk.b, 0u, 1u);                // round-1 subkey
    TF nk  = tf2(rk.a, rk.b, 0u, 0u);                // round-1 carried key
    TF s2k = tf2(nk.a, nk.b, 0u, 1u);                // round-2 subkey
    const unsigned ka = r ? s2k.a : s1k.a;
    const unsigned kb = r ? s2k.b : s1k.b;
    for (int i = tid; i < NN; i += 256) {
      TF t = tf2(ka, kb, 0u, (unsigned)i);
      // composite (key<<32)|position => stable sort incl. key collisions
      s[i] = ((unsigned long long)(t.a ^ t.b) << 32) | (unsigned)i;
    }
    bitonic8192_256(s, tid);
    if (r == 0) {
      unsigned* v1 = v1buf + (size_t)b * NN;
      for (int i = tid; i < NN; i += 256) v1[i] = (unsigned)(s[i] & 0xffffffffu);
    } else {
      for (int t = tid; t < NRAND; t += 256)
        idx[b * NM + NFPS + t] = (int)(s[t] & 0xffffffffu);
    }
  } else {
    // ================= transpose x [B,C,N] -> xT [B,N,C] ========================
    float (*t)[33] = (float(*)[33])smem;
    const int tt = bid - (FPS_BLKS + PERM_BLKS);
    const int n0 = (tt & 255) * 32;
    const int c0 = ((tt >> 8) & 1) * 32;
    const int b = tt >> 9;
    const int tx = tid & 31, ty0 = tid >> 5;  // 32 x 8
#pragma unroll
    for (int r = 0; r < 4; ++r) {
      const int ty = ty0 + r * 8;
      t[ty][tx] = x[((size_t)b * NC + (c0 + ty)) * NN + n0 + tx];
    }
    __syncthreads();
#pragma unroll
    for (int r = 0; r < 4; ++r) {
      const int ty = ty0 + r * 8;
      xT[((size_t)b * NN + (n0 + ty)) * NC + c0 + tx] = t[tx][ty];
    }
  }
}

// ---------------- KNN: one wave per sampled point (self-gathers its sample) ----
__global__ __launch_bounds__(256) void knn_kernel(const float* __restrict__ pos,
                                                  const int* __restrict__ idx,
                                                  const unsigned* __restrict__ v1,
                                                  int* __restrict__ knn) {
  __shared__ unsigned long long lst[4][NK][64]; // [wave][rank][lane], 32 KB
  const int tid = threadIdx.x;
  const int wv = tid >> 6, lane = tid & 63;
  const int g = blockIdx.x * 4 + wv;            // 0..16383
  const int b = g >> 11, mm = g & (NM - 1);
  const float* pb = pos + (size_t)b * 3 * NN;
  const int raw = idx[b * NM + mm];
  const int id = (mm < NFPS) ? raw : (int)v1[(size_t)b * NN + raw];
  const float sx = pb[id], sy = pb[NN + id], sz = pb[2 * NN + id];
  const float sm = __fadd_rn(__fadd_rn(__fmul_rn(sx, sx), __fmul_rn(sy, sy)),
                             __fmul_rn(sz, sz));
  float key[NK]; int kid[NK];
#pragma unroll
  for (int i = 0; i < NK; ++i) { key[i] = __int_as_float(0x7F800000); kid[i] = 0; }
  for (int t = 0; t < NN / 64; ++t) {
    const int n = t * 64 + lane;
    float x = pb[n], y = pb[NN + n], z = pb[2 * NN + n];
    float sn = __fadd_rn(__fadd_rn(__fmul_rn(x, x), __fmul_rn(y, y)), __fmul_rn(z, z));
    float dt = __fadd_rn(__fadd_rn(__fmul_rn(sx, x), __fmul_rn(sy, y)), __fmul_rn(sz, z));
    float d2 = __fsub_rn(__fadd_rn(sm, sn), __fmul_rn(2.0f, dt)); // mirror reference
    const float ck = d2; const int ci = n;
    // branchless sorted insert, descending so olds are read before overwrite;
    // strict < => equal keys keep earlier (smaller-index) candidate first
#pragma unroll
    for (int i = NK - 1; i >= 1; --i) {
      float lo = key[i-1], hi = key[i];
      bool cLo = ck < lo, cHi = ck < hi;
      key[i] = __builtin_amdgcn_fmed3f(ck, lo, hi);
      kid[i] = cLo ? kid[i-1] : (cHi ? ci : kid[i]);
    }
    bool c0 = ck < key[0];
    kid[0] = c0 ? ci : kid[0];
    key[0] = fminf(key[0], ck);
  }
  // dump sorted lists (order-flipped keys) to LDS; same-wave access, no barrier
#pragma unroll
  for (int i = 0; i < NK; ++i) {
    unsigned u = __float_as_uint(key[i]);
    u = (u & 0x80000000u) ? ~u : (u | 0x80000000u);
    lst[wv][i][lane] = ((unsigned long long)u << 32) | (unsigned)kid[i];
  }
  // merge 64 sorted lists: 16 rounds of wave-min; unique composites => safe pop
  int ptr = 0;
  unsigned long long head = lst[wv][0][lane];
  unsigned myn = 0;
  for (int k = 0; k < NK; ++k) {
    unsigned long long mn = head;
#pragma unroll
    for (int off = 32; off > 0; off >>= 1) {
      unsigned long long o = __shfl_xor(mn, off, 64);
      if (o < mn) mn = o;
    }
    if (head == mn) { ++ptr; head = (ptr < NK) ? lst[wv][ptr][lane] : ~0ull; }
    if (lane == k) myn = (unsigned)(mn & 0xffffffffu);
  }
  if (lane < NK) knn[(size_t)g * NK + lane] = (int)myn;
}

// ---------------- fused2: final (blocks 0-1023) + possub (1024-1215) ----------
constexpr int FINAL_BLKS = NB * NM / 16;            // 1024
constexpr int POSSUB_BLKS = (NB * 3 * NM + 255) / 256; // 192

__global__ __launch_bounds__(256) void fused2_kernel(const float* __restrict__ xT,
                                                     const float* __restrict__ pos,
                                                     const int* __restrict__ idx,
                                                     const unsigned* __restrict__ v1,
                                                     const int* __restrict__ knn,
                                                     float* __restrict__ xOut,
                                                     float* __restrict__ posOut) {
  __shared__ float tile[64][17];
  const int tid = threadIdx.x;
  if (blockIdx.x >= FINAL_BLKS) {
    // ---- possub: posOut[b,d,mm] = pos[b,d, compose(idx,v1)] ----
    int i = (blockIdx.x - FINAL_BLKS) * 256 + tid;
    if (i < NB * 3 * NM) {
      int mm = i & (NM - 1);
      int bd = i >> 11;            // b*3 + d
      int d = bd % 3, b = bd / 3;
      int raw = idx[b * NM + mm];
      int id = (mm < NFPS) ? raw : (int)v1[(size_t)b * NN + raw];
      posOut[i] = pos[((size_t)b * 3 + d) * NN + id];
    }
    return;
  }
  // ---- final: weights + gather + weighted sum ----
  const int wv = tid >> 6, lane = tid & 63;
  const int base = blockIdx.x * 16;      // 16 consecutive samples, same batch
  const int b = base >> 11;
  const float* pb = pos + (size_t)b * 3 * NN;
  for (int j = 0; j < 4; ++j) {
    const int ml = wv * 4 + j;           // 0..15
    const int g = base + ml;
    const int mm = g & (NM - 1);
    const int raw = idx[b * NM + mm];
    const int sid = (mm < NFPS) ? raw : (int)v1[(size_t)b * NN + raw];
    const float sx = pb[sid], sy = pb[NN + sid], sz = pb[2 * NN + sid];
    const int kk = lane & 15;
    const int nk = knn[(size_t)g * NK + kk];
    float dx = __fsub_rn(pb[nk], sx);
    float dy = __fsub_rn(pb[NN + nk], sy);
    float dz = __fsub_rn(pb[2 * NN + nk], sz);
    float dd = __fadd_rn(__fadd_rn(__fmul_rn(dx, dx), __fmul_rn(dy, dy)),
                         __fmul_rn(dz, dz));
    float d = __fsqrt_rn(dd);
    d = fmaxf(d, 1e-6f);
    float e = __fdiv_rn(0.0f - d, 0.2f);
    float mx = e;
#pragma unroll
    for (int off = 8; off > 0; off >>= 1) mx = fmaxf(mx, __shfl_xor(mx, off, 16));
    float ex = expf(__fsub_rn(e, mx));
    float sum = ex;
#pragma unroll
    for (int off = 8; off > 0; off >>= 1) sum = __fadd_rn(sum, __shfl_xor(sum, off, 16));
    float wgt = __fdiv_rn(ex, sum);
    float acc = 0.0f;
#pragma unroll
    for (int k = 0; k < NK; ++k) {
      float wk = __shfl(wgt, k, 64);
      int   nn = __shfl(nk, k, 64);
      acc = __fadd_rn(acc, __fmul_rn(wk, xT[((size_t)b * NN + nn) * NC + lane]));
    }
    tile[lane][ml] = acc;
  }
  __syncthreads();
  const int m0 = base & (NM - 1);
  for (int e2 = tid; e2 < 64 * 16; e2 += 256) {
    int c = e2 >> 4, ml = e2 & 15;
    xOut[((size_t)b * NC + c) * NM + m0 + ml] = tile[c][ml];
  }
}

extern "C" void kernel_launch(void* const* d_in, const int* in_sizes, int n_in,
                              void* d_out, int out_size, void* d_ws, size_t ws_size,
                              hipStream_t stream) {
  const float* x   = (const float*)d_in[0];
  const float* pos = (const float*)d_in[1];
  float* xOut   = (float*)d_out;
  float* posOut = xOut + (size_t)NB * NC * NM;

  char* w = (char*)d_ws;
  int*      idx    = (int*)(w + OFF_IDX);
  unsigned* v1     = (unsigned*)(w + OFF_V1);
  int*      knn    = (int*)(w + OFF_KNN);
  float*    xT     = (float*)(w + OFF_XT);

  hipLaunchKernelGGL(fused1_kernel, dim3(FPS_BLKS + PERM_BLKS + TR_BLKS), dim3(256), 0,
                     stream, pos, x, idx, v1, xT);
  hipLaunchKernelGGL(knn_kernel, dim3(NB * NM / 4), dim3(256), 0, stream, pos, idx, v1, knn);
  hipLaunchKernelGGL(fused2_kernel, dim3(FINAL_BLKS + POSSUB_BLKS), dim3(256), 0, stream,
                     xT, pos, idx, v1, knn, xOut, posOut);
}

// Round 7
// 1803.306 us; speedup vs baseline: 1.0542x; 1.0542x over previous
//
#include <hip/hip_runtime.h>

// Problem constants (match reference)
constexpr int NB   = 8;     // batches
constexpr int NC   = 64;    // channels
constexpr int NN   = 8192;  // points
constexpr int NM   = 2048;  // samples
constexpr int NK   = 16;    // knn
constexpr int NFPS = 1433;  // int(2048*0.7)
constexpr int NRAND = NM - NFPS; // 615

// ---------------- workspace layout (bytes) ----------------
constexpr size_t OFF_IDX   = 256;      // int idx[8][2048]
constexpr size_t OFF_V1    = 66048;    // uint v1[8][8192]
constexpr size_t OFF_XT    = 1377280;  // float xT[8][8192][64]

struct TF { unsigned a, b; };

__device__ __forceinline__ TF tf2(unsigned k0, unsigned k1, unsigned c0, unsigned c1) {
  unsigned ks2 = k0 ^ k1 ^ 0x1BD11BDAu;
  unsigned x0 = c0 + k0;
  unsigned x1 = c1 + k1;
#define TF_R(r) { x0 += x1; x1 = (x1 << r) | (x1 >> (32 - r)); x1 ^= x0; }
  TF_R(13) TF_R(15) TF_R(26) TF_R(6)
  x0 += k1;  x1 += ks2 + 1u;
  TF_R(17) TF_R(29) TF_R(16) TF_R(24)
  x0 += ks2; x1 += k0 + 2u;
  TF_R(13) TF_R(15) TF_R(26) TF_R(6)
  x0 += k0;  x1 += k1 + 3u;
  TF_R(17) TF_R(29) TF_R(16) TF_R(24)
  x0 += k1;  x1 += ks2 + 4u;
  TF_R(13) TF_R(15) TF_R(26) TF_R(6)
  x0 += ks2; x1 += k0 + 5u;
#undef TF_R
  TF r; r.a = x0; r.b = x1; return r;
}

// DPP-based wave64 max (VALU latency, no LDS on the chain).
__device__ __forceinline__ float wave_max_dpp(float v) {
  int vi;
  vi = __builtin_amdgcn_update_dpp(__float_as_int(v), __float_as_int(v), 0x111, 0xf, 0xf, false);
  v = fmaxf(v, __int_as_float(vi));
  vi = __builtin_amdgcn_update_dpp(__float_as_int(v), __float_as_int(v), 0x112, 0xf, 0xf, false);
  v = fmaxf(v, __int_as_float(vi));
  vi = __builtin_amdgcn_update_dpp(__float_as_int(v), __float_as_int(v), 0x114, 0xf, 0xf, false);
  v = fmaxf(v, __int_as_float(vi));
  vi = __builtin_amdgcn_update_dpp(__float_as_int(v), __float_as_int(v), 0x118, 0xf, 0xf, false);
  v = fmaxf(v, __int_as_float(vi));
  vi = __builtin_amdgcn_update_dpp(__float_as_int(v), __float_as_int(v), 0x142, 0xa, 0xf, false);
  v = fmaxf(v, __int_as_float(vi));
  vi = __builtin_amdgcn_update_dpp(__float_as_int(v), __float_as_int(v), 0x143, 0xc, 0xf, false);
  v = fmaxf(v, __int_as_float(vi));
  return __int_as_float(__builtin_amdgcn_readlane(__float_as_int(v), 63));
}

// ---------------- fused1: fps (blocks 0-7) + perm (8-23) + transpose (24-4119) ----
// R4-exact version (measured 1237 us). fps occupies 8 CUs; perm and transpose
// are independent (disjoint outputs) and stream through the other 248 CUs in
// fps's shadow. No inter-block communication -> dispatch-order independent.
constexpr int FPS_BLKS = NB;                 // 8
constexpr int PERM_BLKS = 2 * NB;            // 16
constexpr int TR_BLKS = (NN / 32) * (NC / 32) * NB;  // 4096

// bitonic sort over 8192 u64 in LDS, 256 threads (16 pairs/thread/stage)
__device__ void bitonic8192_256(unsigned long long* s, int tid) {
  for (unsigned k = 2; k <= 8192u; k <<= 1) {
    for (unsigned j = k >> 1; j > 0; j >>= 1) {
      __syncthreads();
      for (unsigned t = (unsigned)tid; t < 4096u; t += 256u) {
        unsigned i = ((t & ~(j - 1u)) << 1) | (t & (j - 1u));
        unsigned p = i | j;
        bool up = ((i & k) == 0u);
        unsigned long long a = s[i], c = s[p];
        if ((a > c) == up) { s[i] = c; s[p] = a; }
      }
    }
  }
  __syncthreads();
}

__global__ __launch_bounds__(256, 1) void fused1_kernel(const float* __restrict__ pos,
                                                        const float* __restrict__ x,
                                                        int* __restrict__ idx,
                                                        unsigned* __restrict__ v1buf,
                                                        float* __restrict__ xT) {
  __shared__ __align__(16) char smem[98432];
  const int bid = blockIdx.x;
  const int tid = threadIdx.x;

  if (bid < FPS_BLKS) {
    // ================= FPS: proven R0 config (256 thr, 4 waves) =================
    float* ldsX = (float*)smem;                       // 32 KB
    float* ldsY = (float*)(smem + 32768);             // 32 KB
    float* ldsZ = (float*)(smem + 65536);             // 32 KB
    float2 (*slot)[4] = (float2(*)[4])(smem + 98304); // [2][4]
    const int b = bid;
    const int wv = tid >> 6, lane = tid & 63;
    const float* pb = pos + (size_t)b * 3 * NN;
    float px[32], py[32], pz[32], dist[32];
    const int base = tid * 32;   // tid-major ownership => lane order == index order
    const float4* fx = (const float4*)(pb + base);
    const float4* fy = (const float4*)(pb + NN + base);
    const float4* fz = (const float4*)(pb + 2 * NN + base);
#pragma unroll
    for (int q = 0; q < 8; ++q) {
      float4 a = fx[q], c = fy[q], e = fz[q];
      px[4*q] = a.x; px[4*q+1] = a.y; px[4*q+2] = a.z; px[4*q+3] = a.w;
      py[4*q] = c.x; py[4*q+1] = c.y; py[4*q+2] = c.z; py[4*q+3] = c.w;
      pz[4*q] = e.x; pz[4*q+1] = e.y; pz[4*q+2] = e.z; pz[4*q+3] = e.w;
      ((float4*)(ldsX + base))[q] = a;   // one-time stage
      ((float4*)(ldsY + base))[q] = c;
      ((float4*)(ldsZ + base))[q] = e;
    }
#pragma unroll
    for (int s = 0; s < 32; ++s) dist[s] = 1e10f;
    // inline start index (was rng_setup): jax.random.key(42) -> keys[b] -> randint
    TF kb_ = tf2(0u, 42u, 0u, (unsigned)b);
    TF k2 = tf2(kb_.a, kb_.b, 0u, 1u);
    TF bt = tf2(k2.a, k2.b, 0u, 0u);
    int widx = (int)((bt.a ^ bt.b) & (unsigned)(NN - 1));
    if (tid == 0) idx[b * NM] = widx;
    __syncthreads();
    float cx = ldsX[widx], cy = ldsY[widx], cz = ldsZ[widx];
    for (int it = 1; it < NFPS; ++it) {
      const int par = it & 1;
      float bestv = -1.0f; int bestS = 0;
#pragma unroll
      for (int s = 0; s < 32; ++s) {
        // Mirror numpy/XLA exactly: rn ops, no FMA contraction, ((dx2+dy2)+dz2)
        float dx = __fsub_rn(px[s], cx);
        float dy = __fsub_rn(py[s], cy);
        float dz = __fsub_rn(pz[s], cz);
        float d  = __fadd_rn(__fadd_rn(__fmul_rn(dx, dx), __fmul_rn(dy, dy)),
                             __fmul_rn(dz, dz));
        float nd = fminf(dist[s], d);
        dist[s] = nd;
        bool c = nd > bestv;            // strict > keeps first (smallest) index
        bestv = c ? nd : bestv;
        bestS = c ? s : bestS;
      }
      const int gidx = base + bestS;
      const float wm = wave_max_dpp(bestv);
      unsigned long long msk = __ballot(bestv == wm);  // nonzero: max lane matches
      const int fl = (int)__builtin_ctzll(msk);        // lowest lane = smallest index
      const int widxw = __builtin_amdgcn_readlane(gidx, fl);
      if (lane == 0) slot[par][wv] = make_float2(wm, __int_as_float(widxw));
      __syncthreads();
      float2 s0 = slot[par][0], s1 = slot[par][1], s2 = slot[par][2], s3 = slot[par][3];
      if (s1.x > s0.x) s0 = s1;     // ties keep lower wave = smaller index
      if (s3.x > s2.x) s2 = s3;
      if (s2.x > s0.x) s0 = s2;
      widx = __float_as_int(s0.y);
      cx = ldsX[widx]; cy = ldsY[widx]; cz = ldsZ[widx];  // uniform broadcast reads
      if (tid == 0) idx[b * NM + it] = widx;
    }
  } else if (bid < FPS_BLKS + PERM_BLKS) {
    // ================= permutation sorts (round 0: v1, round 1: rand idx) =======
    unsigned long long* s = (unsigned long long*)smem; // 64 KB
    const int pbl = bid - FPS_BLKS;
    const int b = pbl >> 1, r = pbl & 1;
    TF keyr = tf2(0u, 42u, 0u, 1u);
    TF rk = tf2(keyr.a, keyr.b, 0u, (unsigned)b);
    TF s1k = tf2(rk.a, rk.b, 0u, 1u);                // round-1 subkey
    TF nk  = tf2(rk.a, rk.b, 0u, 0u);                // round-1 carried key
    TF s2k = tf2(nk.a, nk.b, 0u, 1u);                // round-2 subkey
    const unsigned ka = r ? s2k.a : s1k.a;
    const unsigned kb = r ? s2k.b : s1k.b;
    for (int i = tid; i < NN; i += 256) {
      TF t = tf2(ka, kb, 0u, (unsigned)i);
      // composite (key<<32)|position => stable sort incl. key collisions
      s[i] = ((unsigned long long)(t.a ^ t.b) << 32) | (unsigned)i;
    }
    bitonic8192_256(s, tid);
    if (r == 0) {
      unsigned* v1 = v1buf + (size_t)b * NN;
      for (int i = tid; i < NN; i += 256) v1[i] = (unsigned)(s[i] & 0xffffffffu);
    } else {
      for (int t = tid; t < NRAND; t += 256)
        idx[b * NM + NFPS + t] = (int)(s[t] & 0xffffffffu);
    }
  } else {
    // ================= transpose x [B,C,N] -> xT [B,N,C] ========================
    float (*t)[33] = (float(*)[33])smem;
    const int tt = bid - (FPS_BLKS + PERM_BLKS);
    const int n0 = (tt & 255) * 32;
    const int c0 = ((tt >> 8) & 1) * 32;
    const int b = tt >> 9;
    const int tx = tid & 31, ty0 = tid >> 5;  // 32 x 8
#pragma unroll
    for (int r = 0; r < 4; ++r) {
      const int ty = ty0 + r * 8;
      t[ty][tx] = x[((size_t)b * NC + (c0 + ty)) * NN + n0 + tx];
    }
    __syncthreads();
#pragma unroll
    for (int r = 0; r < 4; ++r) {
      const int ty = ty0 + r * 8;
      xT[((size_t)b * NN + (n0 + ty)) * NC + c0 + tx] = t[tx][ty];
    }
  }
}

// ---------------- fused3: knn+final (blocks 0-4095) + possub (4096-4287) -------
// Each knn wave owns one sample; after the 16-round merge (neighbor k in lane
// k) it runs the final softmax + weighted xT sum for that SAME sample in-wave:
// no knn global round-trip, no separate final launch. Sample coords are the
// registers knn already gathered. Arithmetic is copied verbatim from the
// verified final_kernel (same rn ops, same k-order) -> bit-identical.
constexpr int KNN_BLKS = NB * NM / 4;                  // 4096
constexpr int POSSUB_BLKS = (NB * 3 * NM + 255) / 256; // 192

__global__ __launch_bounds__(256) void fused3_kernel(const float* __restrict__ pos,
                                                     const int* __restrict__ idx,
                                                     const unsigned* __restrict__ v1,
                                                     const float* __restrict__ xT,
                                                     float* __restrict__ xOut,
                                                     float* __restrict__ posOut) {
  __shared__ unsigned long long lst[4][NK][64]; // [wave][rank][lane], 32 KB
  __shared__ float tile[64][4];                 // [channel][sample-in-block]
  const int tid = threadIdx.x;
  if (blockIdx.x >= KNN_BLKS) {
    // ---- possub: posOut[b,d,mm] = pos[b,d, compose(idx,v1)] ----
    int i = (blockIdx.x - KNN_BLKS) * 256 + tid;
    if (i < NB * 3 * NM) {
      int mm = i & (NM - 1);
      int bd = i >> 11;            // b*3 + d
      int d = bd % 3, b = bd / 3;
      int raw = idx[b * NM + mm];
      int id = (mm < NFPS) ? raw : (int)v1[(size_t)b * NN + raw];
      posOut[i] = pos[((size_t)b * 3 + d) * NN + id];
    }
    return;
  }
  const int wv = tid >> 6, lane = tid & 63;
  const int g = blockIdx.x * 4 + wv;            // 0..16383
  const int b = g >> 11, mm = g & (NM - 1);
  const float* pb = pos + (size_t)b * 3 * NN;
  const int raw = idx[b * NM + mm];
  const int id = (mm < NFPS) ? raw : (int)v1[(size_t)b * NN + raw];
  const float sx = pb[id], sy = pb[NN + id], sz = pb[2 * NN + id];
  const float sm = __fadd_rn(__fadd_rn(__fmul_rn(sx, sx), __fmul_rn(sy, sy)),
                             __fmul_rn(sz, sz));
  float key[NK]; int kid[NK];
#pragma unroll
  for (int i = 0; i < NK; ++i) { key[i] = __int_as_float(0x7F800000); kid[i] = 0; }
  for (int t = 0; t < NN / 64; ++t) {
    const int n = t * 64 + lane;
    float x = pb[n], y = pb[NN + n], z = pb[2 * NN + n];
    float sn = __fadd_rn(__fadd_rn(__fmul_rn(x, x), __fmul_rn(y, y)), __fmul_rn(z, z));
    float dt = __fadd_rn(__fadd_rn(__fmul_rn(sx, x), __fmul_rn(sy, y)), __fmul_rn(sz, z));
    float d2 = __fsub_rn(__fadd_rn(sm, sn), __fmul_rn(2.0f, dt)); // mirror reference
    const float ck = d2; const int ci = n;
    // branchless sorted insert, descending so olds are read before overwrite;
    // strict < => equal keys keep earlier (smaller-index) candidate first
#pragma unroll
    for (int i = NK - 1; i >= 1; --i) {
      float lo = key[i-1], hi = key[i];
      bool cLo = ck < lo, cHi = ck < hi;
      key[i] = __builtin_amdgcn_fmed3f(ck, lo, hi);
      kid[i] = cLo ? kid[i-1] : (cHi ? ci : kid[i]);
    }
    bool c0 = ck < key[0];
    kid[0] = c0 ? ci : kid[0];
    key[0] = fminf(key[0], ck);
  }
  // dump sorted lists (order-flipped keys) to LDS; same-wave access, no barrier
#pragma unroll
  for (int i = 0; i < NK; ++i) {
    unsigned u = __float_as_uint(key[i]);
    u = (u & 0x80000000u) ? ~u : (u | 0x80000000u);
    lst[wv][i][lane] = ((unsigned long long)u << 32) | (unsigned)kid[i];
  }
  // merge 64 sorted lists: 16 rounds of wave-min; unique composites => safe pop
  int ptr = 0;
  unsigned long long head = lst[wv][0][lane];
  unsigned myn = 0;
  for (int k = 0; k < NK; ++k) {
    unsigned long long mn = head;
#pragma unroll
    for (int off = 32; off > 0; off >>= 1) {
      unsigned long long o = __shfl_xor(mn, off, 64);
      if (o < mn) mn = o;
    }
    if (head == mn) { ++ptr; head = (ptr < NK) ? lst[wv][ptr][lane] : ~0ull; }
    if (lane == k) myn = (unsigned)(mn & 0xffffffffu);
  }
  // ---- final for this sample, in-wave (verbatim final_kernel arithmetic) ----
  const int kk = lane & 15;
  const int nk = (int)__shfl(myn, kk, 64);     // neighbor kk (from lane kk)
  float dx = __fsub_rn(pb[nk], sx);
  float dy = __fsub_rn(pb[NN + nk], sy);
  float dz = __fsub_rn(pb[2 * NN + nk], sz);
  float dd = __fadd_rn(__fadd_rn(__fmul_rn(dx, dx), __fmul_rn(dy, dy)),
                       __fmul_rn(dz, dz));
  float d = __fsqrt_rn(dd);
  d = fmaxf(d, 1e-6f);
  float e = __fdiv_rn(0.0f - d, 0.2f);
  float mx = e;
#pragma unroll
  for (int off = 8; off > 0; off >>= 1) mx = fmaxf(mx, __shfl_xor(mx, off, 16));
  float ex = expf(__fsub_rn(e, mx));
  float sum = ex;
#pragma unroll
  for (int off = 8; off > 0; off >>= 1) sum = __fadd_rn(sum, __shfl_xor(sum, off, 16));
  float wgt = __fdiv_rn(ex, sum);
  float acc = 0.0f;
#pragma unroll
  for (int k = 0; k < NK; ++k) {
    float wk = __shfl(wgt, k, 64);
    int   nn = __shfl(nk, k, 64);
    acc = __fadd_rn(acc, __fmul_rn(wk, xT[((size_t)b * NN + nn) * NC + lane]));
  }
  tile[lane][wv] = acc;   // lane = channel
  __syncthreads();
  // write 64 channels x 4 consecutive samples; 4 threads share a 16B row chunk
  const int m0 = (blockIdx.x * 4) & (NM - 1);
  {
    int c = tid >> 2, ml = tid & 3;
    xOut[((size_t)b * NC + c) * NM + m0 + ml] = tile[c][ml];
  }
}

extern "C" void kernel_launch(void* const* d_in, const int* in_sizes, int n_in,
                              void* d_out, int out_size, void* d_ws, size_t ws_size,
                              hipStream_t stream) {
  const float* x   = (const float*)d_in[0];
  const float* pos = (const float*)d_in[1];
  float* xOut   = (float*)d_out;
  float* posOut = xOut + (size_t)NB * NC * NM;

  char* w = (char*)d_ws;
  int*      idx    = (int*)(w + OFF_IDX);
  unsigned* v1     = (unsigned*)(w + OFF_V1);
  float*    xT     = (float*)(w + OFF_XT);

  hipLaunchKernelGGL(fused1_kernel, dim3(FPS_BLKS + PERM_BLKS + TR_BLKS), dim3(256), 0,
                     stream, pos, x, idx, v1, xT);
  hipLaunchKernelGGL(fused3_kernel, dim3(KNN_BLKS + POSSUB_BLKS), dim3(256), 0, stream,
                     pos, idx, v1, xT, xOut, posOut);
}

// Round 8
// 1561.103 us; speedup vs baseline: 1.2178x; 1.1551x over previous
//
#include <hip/hip_runtime.h>

// Problem constants (match reference)
constexpr int NB   = 8;     // batches
constexpr int NC   = 64;    // channels
constexpr int NN   = 8192;  // points
constexpr int NM   = 2048;  // samples
constexpr int NK   = 16;    // knn
constexpr int NFPS = 1433;  // int(2048*0.7)
constexpr int NRAND = NM - NFPS; // 615

// ---------------- workspace layout (bytes) ----------------
constexpr size_t OFF_IDX   = 256;      // int idx[8][2048]
constexpr size_t OFF_V1    = 66048;    // uint v1[8][8192]
constexpr size_t OFF_XT    = 1377280;  // float xT[8][8192][64]

typedef float v2f __attribute__((ext_vector_type(2)));

struct TF { unsigned a, b; };

__device__ __forceinline__ TF tf2(unsigned k0, unsigned k1, unsigned c0, unsigned c1) {
  unsigned ks2 = k0 ^ k1 ^ 0x1BD11BDAu;
  unsigned x0 = c0 + k0;
  unsigned x1 = c1 + k1;
#define TF_R(r) { x0 += x1; x1 = (x1 << r) | (x1 >> (32 - r)); x1 ^= x0; }
  TF_R(13) TF_R(15) TF_R(26) TF_R(6)
  x0 += k1;  x1 += ks2 + 1u;
  TF_R(17) TF_R(29) TF_R(16) TF_R(24)
  x0 += ks2; x1 += k0 + 2u;
  TF_R(13) TF_R(15) TF_R(26) TF_R(6)
  x0 += k0;  x1 += k1 + 3u;
  TF_R(17) TF_R(29) TF_R(16) TF_R(24)
  x0 += k1;  x1 += ks2 + 4u;
  TF_R(13) TF_R(15) TF_R(26) TF_R(6)
  x0 += ks2; x1 += k0 + 5u;
#undef TF_R
  TF r; r.a = x0; r.b = x1; return r;
}

// DPP-based wave64 max (VALU latency, no LDS on the chain).
__device__ __forceinline__ float wave_max_dpp(float v) {
  int vi;
  vi = __builtin_amdgcn_update_dpp(__float_as_int(v), __float_as_int(v), 0x111, 0xf, 0xf, false);
  v = fmaxf(v, __int_as_float(vi));
  vi = __builtin_amdgcn_update_dpp(__float_as_int(v), __float_as_int(v), 0x112, 0xf, 0xf, false);
  v = fmaxf(v, __int_as_float(vi));
  vi = __builtin_amdgcn_update_dpp(__float_as_int(v), __float_as_int(v), 0x114, 0xf, 0xf, false);
  v = fmaxf(v, __int_as_float(vi));
  vi = __builtin_amdgcn_update_dpp(__float_as_int(v), __float_as_int(v), 0x118, 0xf, 0xf, false);
  v = fmaxf(v, __int_as_float(vi));
  vi = __builtin_amdgcn_update_dpp(__float_as_int(v), __float_as_int(v), 0x142, 0xa, 0xf, false);
  v = fmaxf(v, __int_as_float(vi));
  vi = __builtin_amdgcn_update_dpp(__float_as_int(v), __float_as_int(v), 0x143, 0xc, 0xf, false);
  v = fmaxf(v, __int_as_float(vi));
  return __int_as_float(__builtin_amdgcn_readlane(__float_as_int(v), 63));
}

// ---------------- fused1: fps (blocks 0-7) + perm (8-23) + transpose (24-4119) ----
// R4 skeleton; ONLY change this round: dist loop processes slot PAIRS with
// packed-f32 arith (v_pk_sub/mul/add; min/cmp/sel stay scalar). This exact
// pair-loop passed the harness in R5 (bit-exact per half vs scalar rn ops).
constexpr int FPS_BLKS = NB;                 // 8
constexpr int PERM_BLKS = 2 * NB;            // 16
constexpr int TR_BLKS = (NN / 32) * (NC / 32) * NB;  // 4096

// bitonic sort over 8192 u64 in LDS, 256 threads (16 pairs/thread/stage)
__device__ void bitonic8192_256(unsigned long long* s, int tid) {
  for (unsigned k = 2; k <= 8192u; k <<= 1) {
    for (unsigned j = k >> 1; j > 0; j >>= 1) {
      __syncthreads();
      for (unsigned t = (unsigned)tid; t < 4096u; t += 256u) {
        unsigned i = ((t & ~(j - 1u)) << 1) | (t & (j - 1u));
        unsigned p = i | j;
        bool up = ((i & k) == 0u);
        unsigned long long a = s[i], c = s[p];
        if ((a > c) == up) { s[i] = c; s[p] = a; }
      }
    }
  }
  __syncthreads();
}

__global__ __launch_bounds__(256, 1) void fused1_kernel(const float* __restrict__ pos,
                                                        const float* __restrict__ x,
                                                        int* __restrict__ idx,
                                                        unsigned* __restrict__ v1buf,
                                                        float* __restrict__ xT) {
  __shared__ __align__(16) char smem[98432];
  const int bid = blockIdx.x;
  const int tid = threadIdx.x;

  if (bid < FPS_BLKS) {
    // ================= FPS (256 thr, 4 waves; R0 skeleton + pk dist loop) =======
    float* ldsX = (float*)smem;                       // 32 KB
    float* ldsY = (float*)(smem + 32768);             // 32 KB
    float* ldsZ = (float*)(smem + 65536);             // 32 KB
    float2 (*slot)[4] = (float2(*)[4])(smem + 98304); // [2][4]
    const int b = bid;
    const int wv = tid >> 6, lane = tid & 63;
    const float* pb = pos + (size_t)b * 3 * NN;
    v2f px[16], py[16], pz[16], dist[16];   // 32 points as 16 pairs
    const int base = tid * 32;   // tid-major ownership => lane order == index order
    const float4* fx = (const float4*)(pb + base);
    const float4* fy = (const float4*)(pb + NN + base);
    const float4* fz = (const float4*)(pb + 2 * NN + base);
#pragma unroll
    for (int q = 0; q < 8; ++q) {
      float4 a = fx[q], c = fy[q], e = fz[q];
      px[2*q].x = a.x; px[2*q].y = a.y; px[2*q+1].x = a.z; px[2*q+1].y = a.w;
      py[2*q].x = c.x; py[2*q].y = c.y; py[2*q+1].x = c.z; py[2*q+1].y = c.w;
      pz[2*q].x = e.x; pz[2*q].y = e.y; pz[2*q+1].x = e.z; pz[2*q+1].y = e.w;
      ((float4*)(ldsX + base))[q] = a;   // one-time stage
      ((float4*)(ldsY + base))[q] = c;
      ((float4*)(ldsZ + base))[q] = e;
    }
#pragma unroll
    for (int p = 0; p < 16; ++p) { dist[p].x = 1e10f; dist[p].y = 1e10f; }
    // inline start index: jax.random.key(42) -> keys[b] -> randint
    TF kb_ = tf2(0u, 42u, 0u, (unsigned)b);
    TF k2 = tf2(kb_.a, kb_.b, 0u, 1u);
    TF bt = tf2(k2.a, k2.b, 0u, 0u);
    int widx = (int)((bt.a ^ bt.b) & (unsigned)(NN - 1));
    if (tid == 0) idx[b * NM] = widx;
    __syncthreads();
    float cx = ldsX[widx], cy = ldsY[widx], cz = ldsZ[widx];
    for (int it = 1; it < NFPS; ++it) {
      const int par = it & 1;
      float bestv = -1.0f; int bestS = 0;
      {
        v2f cx2; cx2.x = cx; cx2.y = cx;
        v2f cy2; cy2.x = cy; cy2.y = cy;
        v2f cz2; cz2.x = cz; cz2.y = cz;
#pragma unroll
        for (int p = 0; p < 16; ++p) {
          // Mirror numpy/XLA exactly per half: rn ops, NO fma contraction,
          // ((dx2+dy2)+dz2). contract(off) keeps pk_mul/pk_add separate.
          // (bit-exactness of this pair form verified by R5's passing run)
#pragma clang fp contract(off)
          v2f dx = px[p] - cx2;
          v2f dy = py[p] - cy2;
          v2f dz = pz[p] - cz2;
          v2f d2 = (dx * dx + dy * dy) + dz * dz;
          float nd0 = fminf(dist[p].x, d2.x);
          float nd1 = fminf(dist[p].y, d2.y);
          dist[p].x = nd0; dist[p].y = nd1;
          // per-slot tracking, ascending slot order (2p, 2p+1), strict >
          bool c0 = nd0 > bestv;
          bestv = c0 ? nd0 : bestv;
          bestS = c0 ? 2*p : bestS;
          bool c1 = nd1 > bestv;
          bestv = c1 ? nd1 : bestv;
          bestS = c1 ? 2*p + 1 : bestS;
        }
      }
      const int gidx = base + bestS;
      const float wm = wave_max_dpp(bestv);
      unsigned long long msk = __ballot(bestv == wm);  // nonzero: max lane matches
      const int fl = (int)__builtin_ctzll(msk);        // lowest lane = smallest index
      const int widxw = __builtin_amdgcn_readlane(gidx, fl);
      if (lane == 0) slot[par][wv] = make_float2(wm, __int_as_float(widxw));
      __syncthreads();
      float2 s0 = slot[par][0], s1 = slot[par][1], s2 = slot[par][2], s3 = slot[par][3];
      if (s1.x > s0.x) s0 = s1;     // ties keep lower wave = smaller index
      if (s3.x > s2.x) s2 = s3;
      if (s2.x > s0.x) s0 = s2;
      widx = __float_as_int(s0.y);
      cx = ldsX[widx]; cy = ldsY[widx]; cz = ldsZ[widx];  // uniform broadcast reads
      if (tid == 0) idx[b * NM + it] = widx;
    }
  } else if (bid < FPS_BLKS + PERM_BLKS) {
    // ================= permutation sorts (round 0: v1, round 1: rand idx) =======
    unsigned long long* s = (unsigned long long*)smem; // 64 KB
    const int pbl = bid - FPS_BLKS;
    const int b = pbl >> 1, r = pbl & 1;
    TF keyr = tf2(0u, 42u, 0u, 1u);
    TF rk = tf2(keyr.a, keyr.b, 0u, (unsigned)b);
    TF s1k = tf2(rk.a, rk.b, 0u, 1u);                // round-1 subkey
    TF nk  = tf2(rk.a, rk.b, 0u, 0u);                // round-1 carried key
    TF s2k = tf2(nk.a, nk.b, 0u, 1u);                // round-2 subkey
    const unsigned ka = r ? s2k.a : s1k.a;
    const unsigned kb = r ? s2k.b : s1k.b;
    for (int i = tid; i < NN; i += 256) {
      TF t = tf2(ka, kb, 0u, (unsigned)i);
      // composite (key<<32)|position => stable sort incl. key collisions
      s[i] = ((unsigned long long)(t.a ^ t.b) << 32) | (unsigned)i;
    }
    bitonic8192_256(s, tid);
    if (r == 0) {
      unsigned* v1 = v1buf + (size_t)b * NN;
      for (int i = tid; i < NN; i += 256) v1[i] = (unsigned)(s[i] & 0xffffffffu);
    } else {
      for (int t = tid; t < NRAND; t += 256)
        idx[b * NM + NFPS + t] = (int)(s[t] & 0xffffffffu);
    }
  } else {
    // ================= transpose x [B,C,N] -> xT [B,N,C] ========================
    float (*t)[33] = (float(*)[33])smem;
    const int tt = bid - (FPS_BLKS + PERM_BLKS);
    const int n0 = (tt & 255) * 32;
    const int c0 = ((tt >> 8) & 1) * 32;
    const int b = tt >> 9;
    const int tx = tid & 31, ty0 = tid >> 5;  // 32 x 8
#pragma unroll
    for (int r = 0; r < 4; ++r) {
      const int ty = ty0 + r * 8;
      t[ty][tx] = x[((size_t)b * NC + (c0 + ty)) * NN + n0 + tx];
    }
    __syncthreads();
#pragma unroll
    for (int r = 0; r < 4; ++r) {
      const int ty = ty0 + r * 8;
      xT[((size_t)b * NN + (n0 + ty)) * NC + c0 + tx] = t[tx][ty];
    }
  }
}

// ---------------- fused3: knn+final (blocks 0-4095) + possub (4096-4287) -------
// knn scan now uses float4 point loads; lane owns points t*256+lane*4+j.
// The per-lane candidate PARTITION changes but the global top-16 is a
// partition-invariant: all 8192 points scanned, identical rn d2 floats,
// and the 64-list merge takes the min-16 of UNIQUE (key,idx) composites.
constexpr int KNN_BLKS = NB * NM / 4;                  // 4096
constexpr int POSSUB_BLKS = (NB * 3 * NM + 255) / 256; // 192

__global__ __launch_bounds__(256) void fused3_kernel(const float* __restrict__ pos,
                                                     const int* __restrict__ idx,
                                                     const unsigned* __restrict__ v1,
                                                     const float* __restrict__ xT,
                                                     float* __restrict__ xOut,
                                                     float* __restrict__ posOut) {
  __shared__ unsigned long long lst[4][NK][64]; // [wave][rank][lane], 32 KB
  __shared__ float tile[64][4];                 // [channel][sample-in-block]
  const int tid = threadIdx.x;
  if (blockIdx.x >= KNN_BLKS) {
    // ---- possub: posOut[b,d,mm] = pos[b,d, compose(idx,v1)] ----
    int i = (blockIdx.x - KNN_BLKS) * 256 + tid;
    if (i < NB * 3 * NM) {
      int mm = i & (NM - 1);
      int bd = i >> 11;            // b*3 + d
      int d = bd % 3, b = bd / 3;
      int raw = idx[b * NM + mm];
      int id = (mm < NFPS) ? raw : (int)v1[(size_t)b * NN + raw];
      posOut[i] = pos[((size_t)b * 3 + d) * NN + id];
    }
    return;
  }
  const int wv = tid >> 6, lane = tid & 63;
  const int g = blockIdx.x * 4 + wv;            // 0..16383
  const int b = g >> 11, mm = g & (NM - 1);
  const float* pb = pos + (size_t)b * 3 * NN;
  const int raw = idx[b * NM + mm];
  const int id = (mm < NFPS) ? raw : (int)v1[(size_t)b * NN + raw];
  const float sx = pb[id], sy = pb[NN + id], sz = pb[2 * NN + id];
  const float sm = __fadd_rn(__fadd_rn(__fmul_rn(sx, sx), __fmul_rn(sy, sy)),
                             __fmul_rn(sz, sz));
  float key[NK]; int kid[NK];
#pragma unroll
  for (int i = 0; i < NK; ++i) { key[i] = __int_as_float(0x7F800000); kid[i] = 0; }
  for (int t = 0; t < NN / 256; ++t) {
    const int n0 = t * 256 + lane * 4;
    const float4 xv = *(const float4*)(pb + n0);
    const float4 yv = *(const float4*)(pb + NN + n0);
    const float4 zv = *(const float4*)(pb + 2 * NN + n0);
#pragma unroll
    for (int j = 0; j < 4; ++j) {
      const float x = (j == 0) ? xv.x : (j == 1) ? xv.y : (j == 2) ? xv.z : xv.w;
      const float y = (j == 0) ? yv.x : (j == 1) ? yv.y : (j == 2) ? yv.z : yv.w;
      const float z = (j == 0) ? zv.x : (j == 1) ? zv.y : (j == 2) ? zv.z : zv.w;
      float sn = __fadd_rn(__fadd_rn(__fmul_rn(x, x), __fmul_rn(y, y)), __fmul_rn(z, z));
      float dt = __fadd_rn(__fadd_rn(__fmul_rn(sx, x), __fmul_rn(sy, y)), __fmul_rn(sz, z));
      float d2 = __fsub_rn(__fadd_rn(sm, sn), __fmul_rn(2.0f, dt)); // mirror reference
      const float ck = d2; const int ci = n0 + j;
      // branchless sorted insert, descending so olds are read before overwrite;
      // strict < => equal keys keep earlier candidate first (unique composites
      // make the final merge order exact regardless)
#pragma unroll
      for (int i = NK - 1; i >= 1; --i) {
        float lo = key[i-1], hi = key[i];
        bool cLo = ck < lo, cHi = ck < hi;
        key[i] = __builtin_amdgcn_fmed3f(ck, lo, hi);
        kid[i] = cLo ? kid[i-1] : (cHi ? ci : kid[i]);
      }
      bool c0 = ck < key[0];
      kid[0] = c0 ? ci : kid[0];
      key[0] = fminf(key[0], ck);
    }
  }
  // dump sorted lists (order-flipped keys) to LDS; same-wave access, no barrier
#pragma unroll
  for (int i = 0; i < NK; ++i) {
    unsigned u = __float_as_uint(key[i]);
    u = (u & 0x80000000u) ? ~u : (u | 0x80000000u);
    lst[wv][i][lane] = ((unsigned long long)u << 32) | (unsigned)kid[i];
  }
  // merge 64 sorted lists: 16 rounds of wave-min; unique composites => safe pop
  int ptr = 0;
  unsigned long long head = lst[wv][0][lane];
  unsigned myn = 0;
  for (int k = 0; k < NK; ++k) {
    unsigned long long mn = head;
#pragma unroll
    for (int off = 32; off > 0; off >>= 1) {
      unsigned long long o = __shfl_xor(mn, off, 64);
      if (o < mn) mn = o;
    }
    if (head == mn) { ++ptr; head = (ptr < NK) ? lst[wv][ptr][lane] : ~0ull; }
    if (lane == k) myn = (unsigned)(mn & 0xffffffffu);
  }
  // ---- final for this sample, in-wave (verbatim final_kernel arithmetic) ----
  const int kk = lane & 15;
  const int nk = (int)__shfl(myn, kk, 64);     // neighbor kk (from lane kk)
  float dx = __fsub_rn(pb[nk], sx);
  float dy = __fsub_rn(pb[NN + nk], sy);
  float dz = __fsub_rn(pb[2 * NN + nk], sz);
  float dd = __fadd_rn(__fadd_rn(__fmul_rn(dx, dx), __fmul_rn(dy, dy)),
                       __fmul_rn(dz, dz));
  float d = __fsqrt_rn(dd);
  d = fmaxf(d, 1e-6f);
  float e = __fdiv_rn(0.0f - d, 0.2f);
  float mx = e;
#pragma unroll
  for (int off = 8; off > 0; off >>= 1) mx = fmaxf(mx, __shfl_xor(mx, off, 16));
  float ex = expf(__fsub_rn(e, mx));
  float sum = ex;
#pragma unroll
  for (int off = 8; off > 0; off >>= 1) sum = __fadd_rn(sum, __shfl_xor(sum, off, 16));
  float wgt = __fdiv_rn(ex, sum);
  float acc = 0.0f;
#pragma unroll
  for (int k = 0; k < NK; ++k) {
    float wk = __shfl(wgt, k, 64);
    int   nn = __shfl(nk, k, 64);
    acc = __fadd_rn(acc, __fmul_rn(wk, xT[((size_t)b * NN + nn) * NC + lane]));
  }
  tile[lane][wv] = acc;   // lane = channel
  __syncthreads();
  // write 64 channels x 4 consecutive samples; 4 threads share a 16B row chunk
  const int m0 = (blockIdx.x * 4) & (NM - 1);
  {
    int c = tid >> 2, ml = tid & 3;
    xOut[((size_t)b * NC + c) * NM + m0 + ml] = tile[c][ml];
  }
}

extern "C" void kernel_launch(void* const* d_in, const int* in_sizes, int n_in,
                              void* d_out, int out_size, void* d_ws, size_t ws_size,
                              hipStream_t stream) {
  const float* x   = (const float*)d_in[0];
  const float* pos = (const float*)d_in[1];
  float* xOut   = (float*)d_out;
  float* posOut = xOut + (size_t)NB * NC * NM;

  char* w = (char*)d_ws;
  int*      idx    = (int*)(w + OFF_IDX);
  unsigned* v1     = (unsigned*)(w + OFF_V1);
  float*    xT     = (float*)(w + OFF_XT);

  hipLaunchKernelGGL(fused1_kernel, dim3(FPS_BLKS + PERM_BLKS + TR_BLKS), dim3(256), 0,
                     stream, pos, x, idx, v1, xT);
  hipLaunchKernelGGL(fused3_kernel, dim3(KNN_BLKS + POSSUB_BLKS), dim3(256), 0, stream,
                     pos, idx, v1, xT, xOut, posOut);
}